// Round 7
// baseline (41.456 us; speedup 1.0000x reference)
//
#include <hip/hip_runtime.h>
#include <hip/hip_fp16.h>

// GCN layer: out[N,16] = segment_sum(vals[e] * embeds[col[e], :], row[e])
// Round 7: LDS metadata staging (r6) fixed the vmcnt-entanglement and got
// 63->38us. K2 is still MLP-bound (~30us vs ~7us floor): each 8-edge batch
// drains vmcnt(0) with only 8 gathers outstanding. This round: 16-edge
// batches -> 16 independent gathers in flight per wave, half the drains.

#define D 16
constexpr int BLOCK = 256;
constexpr int NPB = BLOCK / 4;    // 64 nodes per block (4 lanes/node)
constexpr int SMEM_E = 3072;      // staged edges per window (24KB), mult of 16

typedef float f32x4 __attribute__((ext_vector_type(4)));
typedef int   i32x4 __attribute__((ext_vector_type(4)));
typedef unsigned int u32x2 __attribute__((ext_vector_type(2)));
typedef unsigned int u32x4 __attribute__((ext_vector_type(4)));

__device__ inline float2 h2f(unsigned int u) {
  union { unsigned int u; __half2 h; } cv;
  cv.u = u;
  return __half22float2(cv.h);
}

// Fused prep: repack embeds f32->f16 (task A) + row_ptr adjacent-diff (task B).
__global__ __launch_bounds__(BLOCK) void prep_kernel(
    const int* __restrict__ row, int E,
    const float* __restrict__ embeds, int N,
    int* __restrict__ row_ptr, __half* __restrict__ table) {
  const long long t = (long long)blockIdx.x * BLOCK + threadIdx.x;

  if (table != nullptr) {
    const long long nchunkA = (long long)N * 2;  // 8 halves per chunk
    if (t < nchunkA) {
      const f32x4* src = (const f32x4*)embeds + t * 2;
      f32x4 a = __builtin_nontemporal_load(src);
      f32x4 b = __builtin_nontemporal_load(src + 1);
      union { __half2 h[4]; u32x4 u; } o;
      o.h[0] = __floats2half2_rn(a[0], a[1]);
      o.h[1] = __floats2half2_rn(a[2], a[3]);
      o.h[2] = __floats2half2_rn(b[0], b[1]);
      o.h[3] = __floats2half2_rn(b[2], b[3]);
      *((u32x4*)table + t) = o.u;  // cached store: we WANT this in L2
    }
  }

  const long long e = t * 4;
  if (e < E) {
    int prev = (e == 0) ? -1 : row[e - 1];
    const int cnt = (E - e >= 4) ? 4 : (int)(E - e);
    int r[4];
    if (cnt == 4) {
      i32x4 r4 = *(const i32x4*)(row + e);
      r[0] = r4[0]; r[1] = r4[1]; r[2] = r4[2]; r[3] = r4[3];
    } else {
      for (int k = 0; k < cnt; ++k) r[k] = row[e + k];
    }
    for (int k = 0; k < cnt; ++k) {
      for (int n = prev + 1; n <= r[k]; ++n) row_ptr[n] = (int)e + k;
      prev = r[k];
    }
    if (e + cnt == E) {
      for (int n = prev + 1; n <= N; ++n) row_ptr[n] = E;
    }
  }
}

// K2: block stages its nodes' edge window into LDS, then 4-lane groups
// gather fp16 rows in 16-edge batches (16 gathers in flight per wave).
__global__ __launch_bounds__(BLOCK) void gcn_gather_kernel(
    const int* __restrict__ col, const float* __restrict__ vals,
    const __half* __restrict__ table, const int* __restrict__ row_ptr,
    f32x4* __restrict__ out4, int N, int E) {
  __shared__ __align__(16) unsigned int s_meta[SMEM_E * 2];  // {col,valbits}

  const int t = threadIdx.x;
  const int n0 = blockIdx.x * NPB;
  const int nEnd = (n0 + NPB < N) ? n0 + NPB : N;
  const int g = t >> 2;
  const int q = t & 3;
  const int node = n0 + g;
  const bool active = (node < nEnd);

  const int Wb = row_ptr[n0] & ~3;   // aligned window base
  const int We = row_ptr[nEnd];

  const int beg = active ? row_ptr[node] : 0;
  const int end = active ? row_ptr[node + 1] : 0;
  const unsigned q8 = (unsigned)(q << 3);  // byte offset of this lane's 8B
  const char* tbl = (const char*)table;

  f32x4 acc = {0.f, 0.f, 0.f, 0.f};

  for (int W0 = Wb; W0 < We; W0 += SMEM_E) {
    const int cnt  = (SMEM_E < We - W0) ? SMEM_E : (We - W0);
    const int cntP = (cnt + 15) & ~15;   // <= SMEM_E (mult of 16)
    __syncthreads();  // protect s_meta reuse across windows
    // Cooperative coalesced staging: 4 edges per thread per pass.
    for (int i = t * 4; i < cntP; i += BLOCK * 4) {
      const int e = W0 + i;
      u32x4 lo, hi;
      if (e + 3 < E) {
        i32x4 c4 = *(const i32x4*)(col + e);
        f32x4 v4 = *(const f32x4*)(vals + e);
        lo = (u32x4){(unsigned)c4[0], __float_as_uint(v4[0]),
                     (unsigned)c4[1], __float_as_uint(v4[1])};
        hi = (u32x4){(unsigned)c4[2], __float_as_uint(v4[2]),
                     (unsigned)c4[3], __float_as_uint(v4[3])};
      } else {
        unsigned cc[4], vv[4];
        for (int k = 0; k < 4; ++k) {
          cc[k] = (e + k < E) ? (unsigned)col[e + k] : 0u;
          vv[k] = (e + k < E) ? __float_as_uint(vals[e + k]) : 0u;
        }
        lo = (u32x4){cc[0], vv[0], cc[1], vv[1]};
        hi = (u32x4){cc[2], vv[2], cc[3], vv[3]};
      }
      *(u32x4*)(s_meta + (size_t)i * 2)     = lo;
      *(u32x4*)(s_meta + (size_t)i * 2 + 4) = hi;
    }
    __syncthreads();

    const int gb = (beg > W0) ? beg : W0;
    const int ge = (end < W0 + cnt) ? end : (W0 + cnt);
    if (ge > gb) {
      const unsigned span = (unsigned)(ge - gb);
      const int e0 = W0 + ((gb - W0) & ~15);     // 16-aligned within window
      const int e1 = e0 + ((ge - e0 + 15) & ~15);  // <= W0 + cntP
      for (int e = e0; e < e1; e += 16) {
        const int idx = (e - W0) * 2;
        // Metadata via LDS (lgkmcnt); 4-lane same-address reads broadcast.
        u32x4 m0 = *(const u32x4*)(s_meta + idx +  0);  // c0 v0 c1 v1
        u32x4 m1 = *(const u32x4*)(s_meta + idx +  4);
        u32x4 m2 = *(const u32x4*)(s_meta + idx +  8);
        u32x4 m3 = *(const u32x4*)(s_meta + idx + 12);
        u32x4 m4 = *(const u32x4*)(s_meta + idx + 16);
        u32x4 m5 = *(const u32x4*)(s_meta + idx + 20);
        u32x4 m6 = *(const u32x4*)(s_meta + idx + 24);
        u32x4 m7 = *(const u32x4*)(s_meta + idx + 28);
        // 16 independent 8B gathers -> only vmcnt traffic in the loop.
        u32x2 g0  = *(const u32x2*)(tbl + (size_t)((m0[0] << 5) + q8));
        u32x2 g1  = *(const u32x2*)(tbl + (size_t)((m0[2] << 5) + q8));
        u32x2 g2  = *(const u32x2*)(tbl + (size_t)((m1[0] << 5) + q8));
        u32x2 g3  = *(const u32x2*)(tbl + (size_t)((m1[2] << 5) + q8));
        u32x2 g4  = *(const u32x2*)(tbl + (size_t)((m2[0] << 5) + q8));
        u32x2 g5  = *(const u32x2*)(tbl + (size_t)((m2[2] << 5) + q8));
        u32x2 g6  = *(const u32x2*)(tbl + (size_t)((m3[0] << 5) + q8));
        u32x2 g7  = *(const u32x2*)(tbl + (size_t)((m3[2] << 5) + q8));
        u32x2 g8  = *(const u32x2*)(tbl + (size_t)((m4[0] << 5) + q8));
        u32x2 g9  = *(const u32x2*)(tbl + (size_t)((m4[2] << 5) + q8));
        u32x2 g10 = *(const u32x2*)(tbl + (size_t)((m5[0] << 5) + q8));
        u32x2 g11 = *(const u32x2*)(tbl + (size_t)((m5[2] << 5) + q8));
        u32x2 g12 = *(const u32x2*)(tbl + (size_t)((m6[0] << 5) + q8));
        u32x2 g13 = *(const u32x2*)(tbl + (size_t)((m6[2] << 5) + q8));
        u32x2 g14 = *(const u32x2*)(tbl + (size_t)((m7[0] << 5) + q8));
        u32x2 g15 = *(const u32x2*)(tbl + (size_t)((m7[2] << 5) + q8));
#define EDGE(i, gg, vbits)                                            \
        {                                                             \
          float w = ((unsigned)(e + i - gb) < span)                   \
                        ? __uint_as_float(vbits) : 0.f;               \
          float2 lo2 = h2f(gg[0]), hi2 = h2f(gg[1]);                  \
          acc[0] = fmaf(w, lo2.x, acc[0]);                            \
          acc[1] = fmaf(w, lo2.y, acc[1]);                            \
          acc[2] = fmaf(w, hi2.x, acc[2]);                            \
          acc[3] = fmaf(w, hi2.y, acc[3]);                            \
        }
        EDGE( 0, g0,  m0[1])
        EDGE( 1, g1,  m0[3])
        EDGE( 2, g2,  m1[1])
        EDGE( 3, g3,  m1[3])
        EDGE( 4, g4,  m2[1])
        EDGE( 5, g5,  m2[3])
        EDGE( 6, g6,  m3[1])
        EDGE( 7, g7,  m3[3])
        EDGE( 8, g8,  m4[1])
        EDGE( 9, g9,  m4[3])
        EDGE(10, g10, m5[1])
        EDGE(11, g11, m5[3])
        EDGE(12, g12, m6[1])
        EDGE(13, g13, m6[3])
        EDGE(14, g14, m7[1])
        EDGE(15, g15, m7[3])
#undef EDGE
      }
    }
  }

  if (active) {
    __builtin_nontemporal_store(acc, out4 + (size_t)node * 4 + q);
  }
}

// Fallback (f32 gathers straight from embeds) if ws can't hold the table.
__global__ __launch_bounds__(BLOCK) void gcn_node_f32_kernel(
    const int* __restrict__ col, const float* __restrict__ vals,
    const f32x4* __restrict__ embeds4, const int* __restrict__ row_ptr,
    f32x4* __restrict__ out4, int N, int E) {
  const int t = blockIdx.x * BLOCK + threadIdx.x;
  const int node = t >> 2;
  const int q = t & 3;
  if (node >= N) return;
  const int beg = row_ptr[node];
  const int end = row_ptr[node + 1];
  f32x4 acc = {0.f, 0.f, 0.f, 0.f};
  for (int e = beg; e < end; ++e) {
    acc += vals[e] * embeds4[(long long)col[e] * 4 + q];
  }
  __builtin_nontemporal_store(acc, out4 + (long long)node * 4 + q);
}

extern "C" void kernel_launch(void* const* d_in, const int* in_sizes, int n_in,
                              void* d_out, int out_size, void* d_ws, size_t ws_size,
                              hipStream_t stream) {
  const int*   row    = (const int*)d_in[0];
  const int*   col    = (const int*)d_in[1];
  const float* vals   = (const float*)d_in[2];
  const float* embeds = (const float*)d_in[3];

  const int E = in_sizes[0];
  const int N = in_sizes[3] / D;

  const size_t rp_bytes = ((size_t)(N + 1) * 4 + 511) & ~(size_t)511;
  const size_t tbl_bytes = (size_t)N * D * sizeof(__half);
  const bool use_half = (ws_size >= rp_bytes + tbl_bytes) && (E >= 4);

  int*    row_ptr = (int*)d_ws;
  __half* table   = use_half ? (__half*)((char*)d_ws + rp_bytes) : nullptr;

  {
    long long chunksB = ((long long)E + 3) / 4;
    long long chunksA = use_half ? (long long)N * 2 : 0;
    long long threads = chunksB > chunksA ? chunksB : chunksA;
    int grid = (int)((threads + BLOCK - 1) / BLOCK);
    prep_kernel<<<grid, BLOCK, 0, stream>>>(row, E, embeds, N, row_ptr, table);
  }
  if (use_half) {
    int grid = (N + NPB - 1) / NPB;
    gcn_gather_kernel<<<grid, BLOCK, 0, stream>>>(
        col, vals, table, row_ptr, (f32x4*)d_out, N, E);
  } else {
    long long threads = (long long)N * 4;
    int grid = (int)((threads + BLOCK - 1) / BLOCK);
    gcn_node_f32_kernel<<<grid, BLOCK, 0, stream>>>(
        col, vals, (const f32x4*)embeds, row_ptr, (f32x4*)d_out, N, E);
  }
}